// Round 2
// baseline (751.212 us; speedup 1.0000x reference)
//
#include <hip/hip_runtime.h>
#include <math.h>

// Constants fixed by the reference:
// B=2048, L=64, N=1024, E=32, SE=16, F=8, NW=7, S=20, NSH=56, NF=59
#define BLOCK 256

constexpr int L = 64, N = 1024, E = 32, SE = 16, F = 8, S = 20;
constexpr int NSH = 56;
constexpr int NF  = 59;

typedef float f4 __attribute__((ext_vector_type(4)));

// ---------------------------------------------------------------------------
// R2: single fused kernel. One block per row b; thread t owns nodes 4t..4t+3.
//
// Phase A (prep): stage stops row + fc1 weights in LDS; build the 56-wide
//   shared vector (week emb | features | stop-emb sum) in LDS.
// Phase B (static logits): each thread dots shared[0:56] with conv_w[n,0:56]
//   for its 4 nodes and folds in x_dist*w57 + conv_b. conv_w (236 KB) is
//   L2/LLC-resident after the first blocks touch it; the per-block cost is
//   ~224 cached loads + 224 FMAs per thread (~5 us aggregate on VALU).
// Phase C (stream): einsum over L with NT float4 loads (R0 beat R1 by 20 us
//   with NT), then combine + block log-softmax + mask + NT store.
//
// No workspace use at all: statc round-trip (16 MB), sh_f, w56/w58/colconst
// are gone, as are two kernel launches.
// ---------------------------------------------------------------------------
__global__ __launch_bounds__(BLOCK, 4) void fused_markov(
    const float* __restrict__ x,          // [B, L, N]
    const float* __restrict__ x_dist,     // [N]
    const float* __restrict__ x_features, // [B, F]
    const float* __restrict__ x_markov,   // [B, N]
    const int*   __restrict__ stops,      // [B, S]
    const int*   __restrict__ x_week,     // [B]
    const int*   __restrict__ x_mask,     // [B, N]
    const float* __restrict__ stop_emb,   // [N, SE]
    const float* __restrict__ week_emb,   // [NW, E]
    const float* __restrict__ conv_w,     // [N, 59]
    const float* __restrict__ conv_b,     // [N]
    const float* __restrict__ fc1_w,      // [L]
    const float* __restrict__ fc1_b,      // scalar
    float* __restrict__ out)              // [B, N]
{
    constexpr int NWAVE = BLOCK / 64;
    __shared__ float sh_shared[NSH];
    __shared__ float sh_fc1[L];
    __shared__ int   sh_stops[S];
    __shared__ float red_max[NWAVE];
    __shared__ float red_sum[NWAVE];

    const int b = blockIdx.x;
    const int t = threadIdx.x;

    // ---- Phase A0: stage stops + fc1 ----
    if (t < S) sh_stops[t] = stops[b * S + t];
    if (t >= 64 && t < 64 + L) sh_fc1[t - 64] = fc1_w[t - 64];
    __syncthreads();

    // ---- Phase A1: 56-wide shared vector (same accumulation order as before)
    if (t < E) {
        sh_shared[t] = week_emb[x_week[b] * E + t];
    } else if (t < E + F) {
        sh_shared[t] = x_features[b * F + (t - E)];
    } else if (t < NSH) {
        const int j = t - (E + F);
        float s = 0.f;
        #pragma unroll
        for (int k = 0; k < S; ++k)
            s += stop_emb[sh_stops[k] * SE + j];
        sh_shared[t] = s;
    }
    __syncthreads();

    // ---- Phase B: static logits for this thread's 4 nodes ----
    float stat[4], w56r[4], w58r[4];
    #pragma unroll
    for (int i = 0; i < 4; ++i) {
        const int n = 4 * t + i;
        const float* __restrict__ w = conv_w + (size_t)n * NF;
        float s = 0.f;
        #pragma unroll 8
        for (int j = 0; j < NSH; ++j)
            s = fmaf(sh_shared[j], w[j], s);
        w56r[i] = w[NSH];
        w58r[i] = w[NSH + 2];
        stat[i] = s + x_dist[n] * w[NSH + 1] + conv_b[n];
    }

    // ---- Phase C: einsum over L (NT float4 stream) ----
    const f4* xb = (const f4*)(x + (size_t)b * L * N);
    f4 acc = (f4)(0.f);
    #pragma unroll 16
    for (int l = 0; l < L; ++l) {
        const float w = sh_fc1[l];
        const f4 v = __builtin_nontemporal_load(&xb[l * (N / 4) + t]);
        acc[0] = fmaf(w, v[0], acc[0]);
        acc[1] = fmaf(w, v[1], acc[1]);
        acc[2] = fmaf(w, v[2], acc[2]);
        acc[3] = fmaf(w, v[3], acc[3]);
    }
    const float bias = fc1_b[0];

    const float4 mk = ((const float4*)(x_markov + (size_t)b * N))[t];

    float lg[4];
    lg[0] = stat[0] + (acc[0] + bias) * w56r[0] + mk.x * w58r[0];
    lg[1] = stat[1] + (acc[1] + bias) * w56r[1] + mk.y * w58r[1];
    lg[2] = stat[2] + (acc[2] + bias) * w56r[2] + mk.z * w58r[2];
    lg[3] = stat[3] + (acc[3] + bias) * w56r[3] + mk.w * w58r[3];

    // ---- block log-softmax over the 1024 nodes ----
    float lmax = fmaxf(fmaxf(lg[0], lg[1]), fmaxf(lg[2], lg[3]));
    #pragma unroll
    for (int off = 32; off > 0; off >>= 1)
        lmax = fmaxf(lmax, __shfl_down(lmax, off, 64));
    if ((t & 63) == 0) red_max[t >> 6] = lmax;
    __syncthreads();
    float m = red_max[0];
    #pragma unroll
    for (int i = 1; i < NWAVE; ++i) m = fmaxf(m, red_max[i]);

    float se = 0.f;
    #pragma unroll
    for (int i = 0; i < 4; ++i) se += __expf(lg[i] - m);
    #pragma unroll
    for (int off = 32; off > 0; off >>= 1)
        se += __shfl_down(se, off, 64);
    if ((t & 63) == 0) red_sum[t >> 6] = se;
    __syncthreads();
    float Z = 0.f;
    #pragma unroll
    for (int i = 0; i < NWAVE; ++i) Z += red_sum[i];
    const float logZ = m + __logf(Z);

    const int4 mask = ((const int4*)(x_mask + (size_t)b * N))[t];
    f4 res;
    res[0] = mask.x ? -1e8f : (lg[0] - logZ);
    res[1] = mask.y ? -1e8f : (lg[1] - logZ);
    res[2] = mask.z ? -1e8f : (lg[2] - logZ);
    res[3] = mask.w ? -1e8f : (lg[3] - logZ);
    __builtin_nontemporal_store(res, &((f4*)(out + (size_t)b * N))[t]);
}

// ---------------------------------------------------------------------------
extern "C" void kernel_launch(void* const* d_in, const int* in_sizes, int n_in,
                              void* d_out, int out_size, void* d_ws, size_t ws_size,
                              hipStream_t stream) {
    const float* x          = (const float*)d_in[0];
    const float* x_dist     = (const float*)d_in[1];
    const float* x_features = (const float*)d_in[2];
    const float* x_markov   = (const float*)d_in[3];
    const int*   stops      = (const int*)  d_in[4];
    const int*   x_week     = (const int*)  d_in[5];
    const int*   x_mask     = (const int*)  d_in[6];
    const float* stop_emb   = (const float*)d_in[7];
    const float* week_emb   = (const float*)d_in[8];
    const float* conv_w     = (const float*)d_in[9];
    const float* conv_b     = (const float*)d_in[10];
    const float* fc1_w      = (const float*)d_in[11];
    const float* fc1_b      = (const float*)d_in[12];
    float* out = (float*)d_out;

    const int B = in_sizes[5];  // x_week has B elements

    // No workspace use: everything fused into one per-row kernel.
    (void)d_ws; (void)ws_size;

    fused_markov<<<B, BLOCK, 0, stream>>>(x, x_dist, x_features, x_markov,
                                          stops, x_week, x_mask,
                                          stop_emb, week_emb, conv_w, conv_b,
                                          fc1_w, fc1_b, out);
}

// Round 3
// 727.903 us; speedup vs baseline: 1.0320x; 1.0320x over previous
//
#include <hip/hip_runtime.h>
#include <math.h>

// Constants fixed by the reference:
// B=2048, L=64, N=1024, E=32, SE=16, F=8, NW=7, S=20, NSH=56, NF=59
#define BLOCK 256

constexpr int L = 64, N = 1024, E = 32, SE = 16, F = 8, S = 20;
constexpr int NSH = 56;
constexpr int NF  = 59;
constexpr int J   = 8;          // split-K factor over L
constexpr int LJ  = L / J;      // 8 l-values per einsum block

typedef float f4 __attribute__((ext_vector_type(4)));

// ---------------------------------------------------------------------------
// Kernel 1 (prep): blocks [0,B) build the per-row 56-vector
//                  blocks [B, B+N/64) unpack conv_w tail columns
// ---------------------------------------------------------------------------
__global__ void prep(const float* __restrict__ x_features,
                     const int*   __restrict__ stops,
                     const int*   __restrict__ x_week,
                     const float* __restrict__ stop_emb,
                     const float* __restrict__ week_emb,
                     const float* __restrict__ conv_w,
                     const float* __restrict__ x_dist,
                     const float* __restrict__ conv_b,
                     float* __restrict__ sh_out,    // [B, 56]
                     float* __restrict__ w56,       // [N]
                     float* __restrict__ w58,       // [N]
                     float* __restrict__ colconst,  // [N]
                     int B)
{
    const int blk = blockIdx.x;
    const int t = threadIdx.x;   // 64 threads
    if (blk < B) {
        const int b = blk;
        if (t < E) {
            sh_out[b * NSH + t] = week_emb[x_week[b] * E + t];
        } else if (t < E + F) {
            sh_out[b * NSH + t] = x_features[b * F + (t - E)];
        } else if (t < NSH) {
            const int j = t - (E + F);
            float s = 0.f;
            #pragma unroll
            for (int k = 0; k < S; ++k)
                s += stop_emb[stops[b * S + k] * SE + j];
            sh_out[b * NSH + t] = s;
        }
    } else {
        const int n = (blk - B) * 64 + t;
        if (n < N) {
            const float* w = conv_w + (size_t)n * NF;
            w56[n] = w[NSH];
            w58[n] = w[NSH + 2];
            colconst[n] = x_dist[n] * w[NSH + 1] + conv_b[n];
        }
    }
}

// ---------------------------------------------------------------------------
// Kernel 2: static[b,n] = shared[b,:] . conv_w[n,:56] + colconst[n]
// LDS-tiled 64x64 GEMM, K=56. grid = (N/64, B/64), block = 256.  (R0 verbatim)
// ---------------------------------------------------------------------------
__global__ __launch_bounds__(BLOCK, 2) void gemm_static(
    const float* __restrict__ shf,       // [B, 56]
    const float* __restrict__ conv_w,    // [N, 59]
    const float* __restrict__ colconst,  // [N]
    float* __restrict__ statc)           // [B, N]
{
    __shared__ float Ash[64][NSH + 1];
    __shared__ float Bsh[64][NSH + 1];

    const int n0 = blockIdx.x * 64;
    const int b0 = blockIdx.y * 64;
    const int t  = threadIdx.x;

    for (int idx = t; idx < 64 * NSH; idx += BLOCK) {
        const int r = idx / NSH, c = idx % NSH;
        Ash[r][c] = shf[(size_t)(b0 + r) * NSH + c];
        Bsh[r][c] = conv_w[(size_t)(n0 + r) * NF + c];
    }
    __syncthreads();

    const int tx = t & 15, ty = t >> 4;
    float acc[4][4];
    #pragma unroll
    for (int i = 0; i < 4; ++i)
        #pragma unroll
        for (int k = 0; k < 4; ++k) acc[i][k] = 0.f;

    #pragma unroll 8
    for (int j = 0; j < NSH; ++j) {
        float a[4], bb[4];
        #pragma unroll
        for (int i = 0; i < 4; ++i) a[i]  = Ash[ty * 4 + i][j];
        #pragma unroll
        for (int i = 0; i < 4; ++i) bb[i] = Bsh[tx * 4 + i][j];
        #pragma unroll
        for (int i = 0; i < 4; ++i)
            #pragma unroll
            for (int k = 0; k < 4; ++k)
                acc[i][k] = fmaf(a[i], bb[k], acc[i][k]);
    }

    const float4 cc = *(const float4*)&colconst[n0 + tx * 4];
    #pragma unroll
    for (int i = 0; i < 4; ++i) {
        float4 r;
        r.x = acc[i][0] + cc.x;
        r.y = acc[i][1] + cc.y;
        r.z = acc[i][2] + cc.z;
        r.w = acc[i][3] + cc.w;
        *(float4*)&statc[(size_t)(b0 + ty * 4 + i) * N + n0 + tx * 4] = r;
    }
}

// ---------------------------------------------------------------------------
// Kernel 3 (R3 NEW): split-K einsum with a COMPACT address frontier.
// Block (j, b) reads x[b, 8j..8j+8, :] — 32 KB contiguous. With x-major
// dispatch, the ~1024 resident blocks cover a sliding ~32 MB window of x
// (vs 256 MB for one-block-per-row), restoring DRAM row-buffer locality.
// Partial dot products go to ws (L2/LLC-resident for the immediate re-read).
// ---------------------------------------------------------------------------
__global__ __launch_bounds__(BLOCK, 8) void einsum_split(
    const float* __restrict__ x,       // [B, L, N]
    const float* __restrict__ fc1_w,   // [L]
    float* __restrict__ partial)       // [B, J, N]
{
    const int j = blockIdx.x;
    const int b = blockIdx.y;
    const int t = threadIdx.x;

    const f4* xb = (const f4*)(x + ((size_t)b * L + (size_t)j * LJ) * N);
    f4 acc = (f4)(0.f);
    #pragma unroll
    for (int l = 0; l < LJ; ++l) {
        const float w = fc1_w[j * LJ + l];   // uniform -> scalar load
        const f4 v = __builtin_nontemporal_load(&xb[l * (N / 4) + t]);
        acc[0] = fmaf(w, v[0], acc[0]);
        acc[1] = fmaf(w, v[1], acc[1]);
        acc[2] = fmaf(w, v[2], acc[2]);
        acc[3] = fmaf(w, v[3], acc[3]);
    }
    // normal store: keep it cache-resident for the combine kernel
    ((f4*)(partial + ((size_t)b * J + j) * N))[t] = acc;
}

// ---------------------------------------------------------------------------
// Kernel 4 (combine): reduce J partials + statc + markov + log-softmax + mask.
// One block per row; thread t owns cols 4t..4t+3.
// ---------------------------------------------------------------------------
__global__ __launch_bounds__(BLOCK, 4) void combine(
    const float* __restrict__ partial,  // [B, J, N]
    const float* __restrict__ statc,    // [B, N]
    const float* __restrict__ w56,      // [N]
    const float* __restrict__ w58,      // [N]
    const float* __restrict__ x_markov, // [B, N]
    const int*   __restrict__ x_mask,   // [B, N]
    const float* __restrict__ fc1_b,    // scalar
    float* __restrict__ out)            // [B, N]
{
    constexpr int NWAVE = BLOCK / 64;
    __shared__ float red_max[NWAVE];
    __shared__ float red_sum[NWAVE];

    const int b = blockIdx.x;
    const int t = threadIdx.x;

    const f4* pb = (const f4*)(partial + (size_t)b * J * N);
    f4 acc = (f4)(0.f);
    #pragma unroll
    for (int j = 0; j < J; ++j) {
        const f4 v = pb[j * (N / 4) + t];
        acc[0] += v[0];
        acc[1] += v[1];
        acc[2] += v[2];
        acc[3] += v[3];
    }
    const float bias = fc1_b[0];

    const float4 st = ((const float4*)(statc + (size_t)b * N))[t];
    const float4 wa = ((const float4*)w56)[t];
    const float4 wc = ((const float4*)w58)[t];
    const float4 mk = ((const float4*)(x_markov + (size_t)b * N))[t];

    float lg[4];
    lg[0] = st.x + (acc[0] + bias) * wa.x + mk.x * wc.x;
    lg[1] = st.y + (acc[1] + bias) * wa.y + mk.y * wc.y;
    lg[2] = st.z + (acc[2] + bias) * wa.z + mk.z * wc.z;
    lg[3] = st.w + (acc[3] + bias) * wa.w + mk.w * wc.w;

    float lmax = fmaxf(fmaxf(lg[0], lg[1]), fmaxf(lg[2], lg[3]));
    #pragma unroll
    for (int off = 32; off > 0; off >>= 1)
        lmax = fmaxf(lmax, __shfl_down(lmax, off, 64));
    if ((t & 63) == 0) red_max[t >> 6] = lmax;
    __syncthreads();
    float m = red_max[0];
    #pragma unroll
    for (int i = 1; i < NWAVE; ++i) m = fmaxf(m, red_max[i]);

    float se = 0.f;
    #pragma unroll
    for (int i = 0; i < 4; ++i) se += __expf(lg[i] - m);
    #pragma unroll
    for (int off = 32; off > 0; off >>= 1)
        se += __shfl_down(se, off, 64);
    if ((t & 63) == 0) red_sum[t >> 6] = se;
    __syncthreads();
    float Z = 0.f;
    #pragma unroll
    for (int i = 0; i < NWAVE; ++i) Z += red_sum[i];
    const float logZ = m + __logf(Z);

    const int4 mask = ((const int4*)(x_mask + (size_t)b * N))[t];
    f4 res;
    res[0] = mask.x ? -1e8f : (lg[0] - logZ);
    res[1] = mask.y ? -1e8f : (lg[1] - logZ);
    res[2] = mask.z ? -1e8f : (lg[2] - logZ);
    res[3] = mask.w ? -1e8f : (lg[3] - logZ);
    __builtin_nontemporal_store(res, &((f4*)(out + (size_t)b * N))[t]);
}

// ---------------------------------------------------------------------------
extern "C" void kernel_launch(void* const* d_in, const int* in_sizes, int n_in,
                              void* d_out, int out_size, void* d_ws, size_t ws_size,
                              hipStream_t stream) {
    const float* x          = (const float*)d_in[0];
    const float* x_dist     = (const float*)d_in[1];
    const float* x_features = (const float*)d_in[2];
    const float* x_markov   = (const float*)d_in[3];
    const int*   stops      = (const int*)  d_in[4];
    const int*   x_week     = (const int*)  d_in[5];
    const int*   x_mask     = (const int*)  d_in[6];
    const float* stop_emb   = (const float*)d_in[7];
    const float* week_emb   = (const float*)d_in[8];
    const float* conv_w     = (const float*)d_in[9];
    const float* conv_b     = (const float*)d_in[10];
    const float* fc1_w      = (const float*)d_in[11];
    const float* fc1_b      = (const float*)d_in[12];
    float* out = (float*)d_out;

    const int B = in_sizes[5];  // x_week has B elements

    // workspace layout (256-B aligned)
    char* ws = (char*)d_ws;
    float* sh_f     = (float*)(ws);                          // B*56
    float* w56      = (float*)(ws + ((size_t)B * NSH * 4 + 255) / 256 * 256);
    float* w58      = w56 + N;
    float* colconst = w58 + N;
    float* statc    = (float*)((char*)colconst + ((size_t)N * 4 + 255) / 256 * 256);  // B*N
    float* partial  = statc + (size_t)B * N;                 // B*J*N

    prep<<<B + N / 64, 64, 0, stream>>>(x_features, stops, x_week,
                                        stop_emb, week_emb, conv_w, x_dist, conv_b,
                                        sh_f, w56, w58, colconst, B);
    dim3 ggrid(N / 64, B / 64);
    gemm_static<<<ggrid, BLOCK, 0, stream>>>(sh_f, conv_w, colconst, statc);
    dim3 egrid(J, B);
    einsum_split<<<egrid, BLOCK, 0, stream>>>(x, fc1_w, partial);
    combine<<<B, BLOCK, 0, stream>>>(partial, statc, w56, w58, x_markov, x_mask,
                                     fc1_b, out);
}